// Round 8
// baseline (444.102 us; speedup 1.0000x reference)
//
#include <hip/hip_runtime.h>
#include <hip/hip_bf16.h>

#define T_TOK 4096
#define DMODEL 1024
#define DFF 4096
#define NEXP 8
#define ROWS_TOT 8192      // T_TOK * TOPK, fixed
#define ROWS_PAD 8448      // + 256 pad rows for BM=256 tile overrun

typedef __bf16 bf16x8 __attribute__((ext_vector_type(8)));
typedef float f32x4 __attribute__((ext_vector_type(4)));
typedef unsigned short u16;

__device__ __forceinline__ u16 f2bf(float f) {
    __hip_bfloat16 b = __float2bfloat16(f);
    return __builtin_bit_cast(u16, b);
}
__device__ __forceinline__ float bf2f(u16 u) {
    unsigned v = (unsigned)u << 16;
    return __builtin_bit_cast(float, v);
}

// exact-erf GELU via Abramowitz-Stegun 7.1.26 (|eps|<=1.5e-7 << bf16 rounding of h)
__device__ __forceinline__ float fast_gelu(float v) {
    const float x = v * 0.70710678118654752f;
    const float ax = fabsf(x);
    const float t = 1.f / fmaf(0.3275911f, ax, 1.f);
    float p = fmaf(1.061405429f, t, -1.453152027f);
    p = fmaf(p, t, 1.421413741f);
    p = fmaf(p, t, -0.284496736f);
    p = fmaf(p, t, 0.254829592f);
    p *= t;
    const float e = __expf(-ax * ax);
    float erfv = fmaf(-p, e, 1.f);
    erfv = copysignf(erfv, x);
    return 0.5f * v * (1.f + erfv);
}

// ---------------- router: logits, softmax-top2 gates, expert histogram ----------
__global__ void router_kernel(const float* __restrict__ x, const float* __restrict__ Wr,
                              const float* __restrict__ br, int* __restrict__ top_idx,
                              float* __restrict__ gates, int* __restrict__ counts) {
    const int t = blockIdx.x;
    const int lane = threadIdx.x;
    float part[8];
#pragma unroll
    for (int e = 0; e < 8; ++e) part[e] = 0.f;
#pragma unroll
    for (int j = 0; j < 4; ++j) {
        const int d0 = j * 256 + lane * 4;
        const float4 xv = *(const float4*)(x + (size_t)t * DMODEL + d0);
        const float xs[4] = {xv.x, xv.y, xv.z, xv.w};
#pragma unroll
        for (int i = 0; i < 4; ++i) {
            const float4 w0 = *(const float4*)(Wr + (d0 + i) * 8);
            const float4 w1 = *(const float4*)(Wr + (d0 + i) * 8 + 4);
            part[0] += xs[i] * w0.x; part[1] += xs[i] * w0.y;
            part[2] += xs[i] * w0.z; part[3] += xs[i] * w0.w;
            part[4] += xs[i] * w1.x; part[5] += xs[i] * w1.y;
            part[6] += xs[i] * w1.z; part[7] += xs[i] * w1.w;
        }
    }
#pragma unroll
    for (int m = 32; m > 0; m >>= 1)
#pragma unroll
        for (int e = 0; e < 8; ++e) part[e] += __shfl_xor(part[e], m, 64);
    if (lane == 0) {
        float l[8];
#pragma unroll
        for (int e = 0; e < 8; ++e) l[e] = part[e] + br[e];
        int i1 = 0;
#pragma unroll
        for (int e = 1; e < 8; ++e) if (l[e] > l[i1]) i1 = e;   // first-index tiebreak
        int i2 = (i1 == 0) ? 1 : 0;
#pragma unroll
        for (int e = 0; e < 8; ++e) if (e != i1 && l[e] > l[i2]) i2 = e;
        const float e2 = expf(l[i2] - l[i1]);
        const float inv = 1.f / (1.f + e2);
        top_idx[t * 2 + 0] = i1;  gates[t * 2 + 0] = inv;
        top_idx[t * 2 + 1] = i2;  gates[t * 2 + 1] = e2 * inv;
        atomicAdd(&counts[i1], 1);
        atomicAdd(&counts[i2], 1);
    }
}

// ---------------- fused scan + fill (single block; LDS cursors) ------------------
__global__ void fillscan_kernel(const int* __restrict__ top_idx, const int* __restrict__ counts,
                                int* __restrict__ offs, int* __restrict__ rowtoken,
                                int* __restrict__ slotof) {
    __shared__ int lcur[8];
    if (threadIdx.x == 0) {
        int s = 0;
        for (int e = 0; e < 8; ++e) { offs[e] = s; lcur[e] = s; s += counts[e]; }
        offs[8] = s;
    }
    __syncthreads();
    for (int t = threadIdx.x; t < T_TOK; t += 1024) {
#pragma unroll
        for (int k = 0; k < 2; ++k) {
            const int e = top_idx[t * 2 + k];
            const int p = atomicAdd(&lcur[e], 1);
            rowtoken[p] = t;
            slotof[t * 2 + k] = p;
        }
    }
}

// ---------------- gather x rows (fp32 -> bf16) into sorted order -----------------
__global__ void gather_kernel(const float* __restrict__ x, const int* __restrict__ rowtoken,
                              u16* __restrict__ Xg) {
    const int p = blockIdx.x;
    const int t = rowtoken[p];
    const int d = threadIdx.x * 4;
    const float4 v = *(const float4*)(x + (size_t)t * DMODEL + d);
    ushort4 o;
    o.x = f2bf(v.x); o.y = f2bf(v.y); o.z = f2bf(v.z); o.w = f2bf(v.w);
    *(ushort4*)(Xg + (size_t)p * DMODEL + d) = o;
}

// ---------------- transpose + fp32->bf16 weight conversion -----------------------
// src [batch][R][C] f32 -> dst [batch][C][R] bf16
__global__ __launch_bounds__(256) void transpose_convert_kernel(
    const float* __restrict__ src, u16* __restrict__ dst, int R, int C) {
    __shared__ float tile[64][65];
    const size_t base = (size_t)blockIdx.z * R * C;
    const int r0 = blockIdx.y * 64, c0 = blockIdx.x * 64;
    const int tr = threadIdx.x >> 4;
    const int tc4 = (threadIdx.x & 15) * 4;
#pragma unroll
    for (int i = 0; i < 4; ++i) {
        const int r = tr + i * 16;
        const float4 v = *(const float4*)(src + base + (size_t)(r0 + r) * C + c0 + tc4);
        tile[r][tc4 + 0] = v.x; tile[r][tc4 + 1] = v.y;
        tile[r][tc4 + 2] = v.z; tile[r][tc4 + 3] = v.w;
    }
    __syncthreads();
#pragma unroll
    for (int i = 0; i < 4; ++i) {
        const int rr = tr + i * 16;
        ushort4 o;
        o.x = f2bf(tile[tc4 + 0][rr]);
        o.y = f2bf(tile[tc4 + 1][rr]);
        o.z = f2bf(tile[tc4 + 2][rr]);
        o.w = f2bf(tile[tc4 + 3][rr]);
        *(ushort4*)(dst + base + (size_t)(c0 + rr) * R + r0 + tc4) = o;
    }
}

// ---------------- grouped GEMM, 256x256 tile, m201-faithful 8-phase pipeline -----
// Phase p = { reads_p; stage_p; BAR; (auto-lgkm) setprio+16 MFMA; BAR }.
// Reads issued BEFORE the barrier: ds latency overlaps the barrier wait.
// vmcnt(6) ONLY at phase-4/8 ends (3 half-tiles = 6 loads in flight, m201's N);
// tail bodies fall back to vmcnt(0). Stage stream (tile parity compile-time):
//   ph1:A1[c+1] ph2:A0[c+2] ph3:B0[c+2] ph4:B1[c+2] ph5:A1[c+2]
//   ph6:A0[c+3] ph7:B0[c+3] ph8:B1[c+3]
// Every slot's overwrite is >=1 full barrier window after its last read: the
// reader's auto-lgkm drains before its MFMA, which precedes the BAR that any
// staging wave must pass -> race-free. T2 both-sides XOR swizzle (0 conflicts),
// T5 setprio. All of KTOT/NTOT/KH compile-time: addresses fold to immediates.
template<int KTOT, int NTOT, int KH, bool GELU>
__global__ __launch_bounds__(512, 2) void gemm8ph_kernel(
    const u16* __restrict__ Amat, const u16* __restrict__ Bmat,
    const float* __restrict__ bias,
    u16* __restrict__ C0, u16* __restrict__ C1,
    const int* __restrict__ offs, const int* __restrict__ counts) {
    constexpr int J  = KTOT / (KH * 64);   // K-tiles per block
    constexpr int NT = NTOT / 256;
    constexpr int GM = 6;

    int bid = blockIdx.x;
    const int e  = bid & 7;   bid >>= 3;
    const int kh = bid % KH;  bid /= KH;
    const int tn = bid % NT;  bid /= NT;
    const int tm0 = bid;
    const int cnt = counts[e];
    if (tm0 * 256 >= cnt) return;
    const int pend  = offs[e] + cnt;
    const int nbase = tn * 256;
    const int k0 = kh * (J * 64);
    u16* __restrict__ Cmat = kh ? C1 : C0;

    __shared__ __align__(16) u16 As[2][2][128 * 64];
    __shared__ __align__(16) u16 Bs[2][2][128 * 64];

    const int tid = threadIdx.x;
    const int lane = tid & 63, wid = tid >> 6;
    const int wr = (wid >> 2) * 64;      // row offset within 128-row half
    const int wc = (wid & 3) * 32;       // col offset within 128-col half
    const int fr = lane & 15, fg = lane >> 4;
    const int rsw = (fr & 7) * 8;        // read-side XOR (elements)

    // stage: 16B chunk c = tid + 512*i -> LDS row (tid>>3)+64*i of a 128x64 half;
    // global col pre-swizzled so the LDS-linear write lands swizzled data.
    const int srow = tid >> 3;
    const int scol = 8 * ((tid & 7) ^ ((tid >> 3) & 7));
    const u16* Bpt = Bmat + (size_t)e * NTOT * KTOT
                          + (size_t)(nbase + srow) * KTOT + k0 + scol;

    float bv[2][2];
#pragma unroll
    for (int q = 0; q < 2; ++q)
#pragma unroll
        for (int n = 0; n < 2; ++n)
            bv[q][n] = GELU ? bias[e * NTOT + nbase + q * 128 + wc + n * 16 + fr] : 0.f;

    for (int tm = tm0; tm * 256 < cnt; tm += GM) {
        const int pbase = offs[e] + tm * 256;
        const u16* Apt = Amat + (size_t)(pbase + srow) * KTOT + k0 + scol;

        f32x4 acc[2][2][4][2];
#pragma unroll
        for (int qm = 0; qm < 2; ++qm)
#pragma unroll
            for (int qn = 0; qn < 2; ++qn)
#pragma unroll
                for (int m = 0; m < 4; ++m)
#pragma unroll
                    for (int n = 0; n < 2; ++n)
                        acc[qm][qn][m][n] = (f32x4){0.f, 0.f, 0.f, 0.f};

        bf16x8 aA[4][2], bB0[2][2], bB1[2][2];

        auto stgA = [&](int buf, int h, int tile) {   // buf,h literal at call site
#pragma unroll
            for (int i = 0; i < 2; ++i)
                __builtin_amdgcn_global_load_lds(
                    (const __attribute__((address_space(1))) void*)
                        (Apt + ((size_t)tile << 6) + (size_t)(h * 128 + 64 * i) * KTOT),
                    (__attribute__((address_space(3))) void*)(&As[buf][h][(size_t)(tid + 512 * i) * 8]),
                    16, 0, 0);
        };
        auto stgB = [&](int buf, int h, int tile) {
#pragma unroll
            for (int i = 0; i < 2; ++i)
                __builtin_amdgcn_global_load_lds(
                    (const __attribute__((address_space(1))) void*)
                        (Bpt + ((size_t)tile << 6) + (size_t)(h * 128 + 64 * i) * KTOT),
                    (__attribute__((address_space(3))) void*)(&Bs[buf][h][(size_t)(tid + 512 * i) * 8]),
                    16, 0, 0);
        };
        auto rdA = [&](int buf, int h) {
#pragma unroll
            for (int m = 0; m < 4; ++m)
#pragma unroll
                for (int kc = 0; kc < 2; ++kc)
                    aA[m][kc] = *(const bf16x8*)(&As[buf][h][
                        (wr + m * 16 + fr) * 64 + ((kc * 32 + fg * 8) ^ rsw)]);
        };
        auto rdB = [&](bf16x8 (&dst)[2][2], int buf, int h) {
#pragma unroll
            for (int n = 0; n < 2; ++n)
#pragma unroll
                for (int kc = 0; kc < 2; ++kc)
                    dst[n][kc] = *(const bf16x8*)(&Bs[buf][h][
                        (wc + n * 16 + fr) * 64 + ((kc * 32 + fg * 8) ^ rsw)]);
        };
        auto mma = [&](int qm, int qn, bf16x8 (&bb)[2][2]) {
            __builtin_amdgcn_s_setprio(1);
#pragma unroll
            for (int kc = 0; kc < 2; ++kc)
#pragma unroll
                for (int m = 0; m < 4; ++m)
#pragma unroll
                    for (int n = 0; n < 2; ++n)
                        acc[qm][qn][m][n] = __builtin_amdgcn_mfma_f32_16x16x32_bf16(
                            aA[m][kc], bb[n][kc], acc[qm][qn][m][n], 0, 0, 0);
            __builtin_amdgcn_s_setprio(0);
        };
        auto bar = [&]() {
            asm volatile("" ::: "memory");
            __builtin_amdgcn_s_barrier();
            asm volatile("" ::: "memory");
        };

        // prologue: tile0 fully (first 8 loads), tile1 minus A1 (body ph1 stages it)
        stgA(0, 0, 0); stgB(0, 0, 0); stgB(0, 1, 0); stgA(0, 1, 0);
        stgA(1, 0, 1); stgB(1, 0, 1); stgB(1, 1, 1);
        asm volatile("s_waitcnt vmcnt(6)" ::: "memory");   // tile0's 4 halves landed
        bar();

#pragma unroll 1
        for (int it2 = 0; it2 < J / 2; ++it2) {
            const int cur = it2 * 2;
            const bool s2 = (cur + 2 < J);
            const bool s3 = (cur + 3 < J);
            // ph1: Q(0,0) of tile cur
            rdA(0, 0); rdB(bB0, 0, 0);
            stgA(1, 1, cur + 1);
            bar(); mma(0, 0, bB0); bar();
            // ph2: Q(0,1)
            rdB(bB1, 0, 1);
            if (s2) stgA(0, 0, cur + 2);
            bar(); mma(0, 1, bB1); bar();
            // ph3: Q(1,1)
            rdA(0, 1);
            if (s2) stgB(0, 0, cur + 2);
            bar(); mma(1, 1, bB1); bar();
            // ph4: Q(1,0); counted vmcnt guards tile cur+1's reads (next window)
            if (s2) stgB(0, 1, cur + 2);
            bar(); mma(1, 0, bB0);
            if (s2) asm volatile("s_waitcnt vmcnt(6)" ::: "memory");
            else    asm volatile("s_waitcnt vmcnt(0)" ::: "memory");
            bar();
            // ph5: Q(0,0) of tile cur+1
            rdA(1, 0); rdB(bB0, 1, 0);
            if (s2) stgA(0, 1, cur + 2);
            bar(); mma(0, 0, bB0); bar();
            // ph6: Q(0,1)
            rdB(bB1, 1, 1);
            if (s3) stgA(1, 0, cur + 3);
            bar(); mma(0, 1, bB1); bar();
            // ph7: Q(1,1)
            rdA(1, 1);
            if (s3) stgB(1, 0, cur + 3);
            bar(); mma(1, 1, bB1); bar();
            // ph8: Q(1,0); counted vmcnt guards tile cur+2's reads
            if (s3) stgB(1, 1, cur + 3);
            bar(); mma(1, 0, bB0);
            if (s3) asm volatile("s_waitcnt vmcnt(6)" ::: "memory");
            else    asm volatile("s_waitcnt vmcnt(0)" ::: "memory");
            bar();
        }

        // epilogue
#pragma unroll
        for (int qm = 0; qm < 2; ++qm) {
#pragma unroll
            for (int m = 0; m < 4; ++m) {
#pragma unroll
                for (int r = 0; r < 4; ++r) {
                    const int p = pbase + qm * 128 + wr + m * 16 + fg * 4 + r;
                    if (p >= pend) continue;
#pragma unroll
                    for (int qn = 0; qn < 2; ++qn) {
#pragma unroll
                        for (int n = 0; n < 2; ++n) {
                            const int col = nbase + qn * 128 + wc + n * 16 + fr;
                            float v = acc[qm][qn][m][n][r];
                            if (GELU) v = fast_gelu(v + bv[qn][n]);
                            Cmat[(size_t)p * NTOT + col] = f2bf(v);
                        }
                    }
                }
            }
        }
    }
}

// ------- combine: out[t] = sum_k g_k * (y0[p_k] + y1[p_k] + b2[e_k]) -------------
__global__ void combine_kernel(const u16* __restrict__ ybuf0, const u16* __restrict__ ybuf1,
                               const float* __restrict__ b2,
                               const int* __restrict__ top_idx, const float* __restrict__ gates,
                               const int* __restrict__ slotof, float* __restrict__ out) {
    const int t = blockIdx.x;
    const int d = threadIdx.x * 4;
    const int e0 = top_idx[t * 2 + 0], e1 = top_idx[t * 2 + 1];
    const float g0 = gates[t * 2 + 0], g1 = gates[t * 2 + 1];
    const int p0 = slotof[t * 2 + 0], p1 = slotof[t * 2 + 1];
    const ushort4 ya0 = *(const ushort4*)(ybuf0 + (size_t)p0 * DMODEL + d);
    const ushort4 ya1 = *(const ushort4*)(ybuf1 + (size_t)p0 * DMODEL + d);
    const ushort4 yb0 = *(const ushort4*)(ybuf0 + (size_t)p1 * DMODEL + d);
    const ushort4 yb1 = *(const ushort4*)(ybuf1 + (size_t)p1 * DMODEL + d);
    const float4 ba = *(const float4*)(b2 + e0 * DMODEL + d);
    const float4 bb = *(const float4*)(b2 + e1 * DMODEL + d);
    float4 o;
    o.x = g0 * (bf2f(ya0.x) + bf2f(ya1.x) + ba.x) + g1 * (bf2f(yb0.x) + bf2f(yb1.x) + bb.x);
    o.y = g0 * (bf2f(ya0.y) + bf2f(ya1.y) + ba.y) + g1 * (bf2f(yb0.y) + bf2f(yb1.y) + bb.y);
    o.z = g0 * (bf2f(ya0.z) + bf2f(ya1.z) + ba.z) + g1 * (bf2f(yb0.z) + bf2f(yb1.z) + bb.z);
    o.w = g0 * (bf2f(ya0.w) + bf2f(ya1.w) + ba.w) + g1 * (bf2f(yb0.w) + bf2f(yb1.w) + bb.w);
    *(float4*)(out + (size_t)t * DMODEL + d) = o;
}

extern "C" void kernel_launch(void* const* d_in, const int* in_sizes, int n_in,
                              void* d_out, int out_size, void* d_ws, size_t ws_size,
                              hipStream_t stream) {
    const float* x  = (const float*)d_in[0];
    const float* Wr = (const float*)d_in[1];
    const float* br = (const float*)d_in[2];
    const float* W1 = (const float*)d_in[3];
    const float* b1 = (const float*)d_in[4];
    const float* W2 = (const float*)d_in[5];
    const float* b2 = (const float*)d_in[6];
    float* out = (float*)d_out;

    // workspace carve (all 16B aligned)
    char* w = (char*)d_ws;
    int*   counts   = (int*)(w + 0);          // 32 B
    int*   offs     = (int*)(w + 64);         // 64 B
    int*   top_idx  = (int*)(w + 1024);                   // 32 KB
    float* gates    = (float*)(w + 1024 + 32768);         // 32 KB
    int*   rowtoken = (int*)(w + 1024 + 65536);           // 40 KB reserved
    int*   slotof   = (int*)(w + 1024 + 65536 + 40960);   // 32 KB
    u16*   Xg       = (u16*)(w + 1024 + 65536 + 40960 + 32768);
    u16*   hbuf     = Xg + (size_t)ROWS_PAD * DMODEL;
    u16*   W1T      = hbuf + (size_t)ROWS_PAD * DFF;
    u16*   W2T      = W1T + (size_t)NEXP * DFF * DMODEL;
    u16*   ybuf0    = Xg;    // Xg dead after ffn1  [ROWS_PAD][DMODEL]
    u16*   ybuf1    = W1T;   // W1T dead after ffn1 [ROWS_PAD][DMODEL] (fits: 17MB < 64MB)
    const size_t need = (size_t)(1024 + 65536 + 40960 + 32768)
        + (size_t)ROWS_PAD * DMODEL * 2 + (size_t)ROWS_PAD * DFF * 2
        + (size_t)NEXP * DFF * DMODEL * 4;
    if (ws_size < need) return;  // fail loudly (absmax) rather than corrupt memory

    hipMemsetAsync(d_ws, 0, 64, stream);  // counts

    // weight transpose/convert: W1 [e][1024][4096] -> W1T [e][4096][1024]
    transpose_convert_kernel<<<dim3(64, 16, 8), 256, 0, stream>>>(W1, W1T, DMODEL, DFF);
    // W2 [e][4096][1024] -> W2T [e][1024][4096]
    transpose_convert_kernel<<<dim3(16, 64, 8), 256, 0, stream>>>(W2, W2T, DFF, DMODEL);

    router_kernel<<<T_TOK, 64, 0, stream>>>(x, Wr, br, top_idx, gates, counts);
    fillscan_kernel<<<1, 1024, 0, stream>>>(top_idx, counts, offs, rowtoken, slotof);
    gather_kernel<<<ROWS_TOT, 256, 0, stream>>>(x, rowtoken, Xg);

    // ffn1: h = gelu(Xg @ W1T^T + b1); KTOT=1024, J=16, KH=1
    // grid = GM(6) x NT(16) x KH(1) x E(8) = 768, active-first, e-inner XCD pin
    gemm8ph_kernel<1024, 4096, 1, true><<<768, 512, 0, stream>>>(
        Xg, W1T, b1, hbuf, nullptr, offs, counts);
    // ffn2: y = h @ W2T^T; KTOT=4096, split-K=2 (J=32 each)
    // grid = GM(6) x NT(4) x KH(2) x E(8) = 384
    gemm8ph_kernel<4096, 1024, 2, false><<<384, 512, 0, stream>>>(
        hbuf, W2T, nullptr, ybuf0, ybuf1, offs, counts);
    // combine: one block per token
    combine_kernel<<<T_TOK, 256, 0, stream>>>(ybuf0, ybuf1, b2, top_idx, gates, slotof, out);
}